// Round 2
// baseline (6572.492 us; speedup 1.0000x reference)
//
#include <hip/hip_runtime.h>

// Problem constants
#define BATCH 256
#define TT    64
#define HH    256
#define DD    8

// Tiling: 2 stacks * 32 batch-blocks of BW=8 -> 64 WGs, 1024 thr (16 waves)
// BW=8 fills MFMA M-rows (G3/G4 full 16, G1/G2 8) and halves per-step weight
// re-fetch volume vs BW=4 (the round-1 bottleneck: L2-miss weight streaming).
#define BW    8
#define NTHR  1024
#define NBLK  (2 * (BATCH / BW))

typedef __attribute__((ext_vector_type(8))) short bfrag;   // 8 bf16 (MFMA A/B operand)
typedef __attribute__((ext_vector_type(4))) float f4;      // MFMA C/D
typedef __attribute__((ext_vector_type(4))) unsigned int uv4;
typedef __attribute__((ext_vector_type(2))) unsigned int uv2;

#define SWZ(g) ((((g) & 31) << 3) | ((g) >> 5))

__device__ __forceinline__ float rcpf(float x) { return __builtin_amdgcn_rcpf(x); }
__device__ __forceinline__ float sigf(float x) { return rcpf(1.0f + __expf(-x)); }
__device__ __forceinline__ float tanh_fast(float x) {
  const float e = __expf(-2.0f * x);
  return __builtin_fmaf(2.0f, rcpf(1.0f + e), -1.0f);
}
__device__ __forceinline__ unsigned short f2bf(float f) {
  union { float f; unsigned int u; } v; v.f = f;
  return (unsigned short)((v.u + 0x7fffu + ((v.u >> 16) & 1u)) >> 16);
}
__device__ __forceinline__ float bf_lo(unsigned int u) {
  union { unsigned int u; float f; } v; v.u = u << 16; return v.f;
}
__device__ __forceinline__ float bf_hi(unsigned int u) {
  union { unsigned int u; float f; } v; v.u = u & 0xffff0000u; return v.f;
}
__device__ __forceinline__ bfrag zero_frag() {
  bfrag r;
#pragma unroll
  for (int x = 0; x < 8; x++) r[x] = 0;
  return r;
}
__device__ __forceinline__ f4 mfma16(bfrag a, bfrag b, f4 c) {
  return __builtin_amdgcn_mfma_f32_16x16x32_bf16(a, b, c, 0, 0, 0);
}

// ---------- weight fragment layout (UNCHANGED) ----------
#define W1_ELEMS  196608
#define STACK_W   (3 * W1_ELEMS)
#define B3_OFF    (2 * STACK_W)
#define B4_OFF    (B3_OFF + 131072)
#define WF_TOTAL  (B4_OFF + 131072)

__global__ __launch_bounds__(256) void prep_weights(
    const float* __restrict__ g1_Whh0, const float* __restrict__ g1_Wih1, const float* __restrict__ g1_Whh1,
    const float* __restrict__ g2_Whh0, const float* __restrict__ g2_Wih1, const float* __restrict__ g2_Whh1,
    const float* __restrict__ attn_W, const float* __restrict__ fc_W,
    unsigned short* __restrict__ wf) {
  const int id = blockIdx.x * 256 + threadIdx.x;
  if (id >= WF_TOTAL) return;
  float src;
  if (id < 2 * STACK_W) {
    const int s = id / STACK_W, r = id % STACK_W;
    const int mm = r / W1_ELEMS, e = r % W1_ELEMS;
    const int j = e & 7, lane = (e >> 3) & 63, c = (e >> 9) & 7, t = e >> 12;
    const int nt = t / 3, g = t % 3;
    const int n = nt * 16 + (lane & 15);
    const int k = c * 32 + ((lane >> 4) << 3) + j;
    const float* W = (mm == 0) ? (s ? g2_Whh0 : g1_Whh0)
                   : (mm == 1) ? (s ? g2_Wih1 : g1_Wih1)
                               : (s ? g2_Whh1 : g1_Whh1);
    src = W[(g * 256 + n) * 256 + k];
  } else if (id < B4_OFF) {
    const int e = id - B3_OFF;
    const int j = e & 7, lane = (e >> 3) & 63, c = (e >> 9) & 7, t = e >> 12;
    const int n = t * 16 + (lane & 15);
    const int k = c * 32 + ((lane >> 4) << 3) + j;
    src = (n < 256) ? attn_W[n * 512 + k] : attn_W[(n - 256) * 512 + 256 + k];
  } else {
    const int e = id - B4_OFF;
    const int j = e & 7, lane = (e >> 3) & 63, c = (e >> 9) & 15, t = e >> 13;
    const int n = t * 16 + (lane & 15);
    const int k = c * 32 + ((lane >> 4) << 3) + j;
    src = fc_W[n * 512 + k];
  }
  wf[id] = f2bf(src);
}

__global__ __launch_bounds__(NTHR, 4) void gru_attn(
    const float* __restrict__ received,
    const float* __restrict__ g1_Wih0, const float* __restrict__ g1_bih0, const float* __restrict__ g1_bhh0,
    const float* __restrict__ g1_bih1, const float* __restrict__ g1_bhh1,
    const float* __restrict__ g2_Wih0, const float* __restrict__ g2_bih0, const float* __restrict__ g2_bhh0,
    const float* __restrict__ g2_bih1, const float* __restrict__ g2_bhh1,
    const float* __restrict__ fc_b, const float* __restrict__ v_W, const float* __restrict__ out_W,
    const unsigned short* __restrict__ wf,
    unsigned short* __restrict__ buf_g, unsigned short* __restrict__ ehb_g,
    float* __restrict__ ws_p) {
  const int tid  = threadIdx.x;
  const int lane = tid & 63, wave = tid >> 6;      // 16 waves
  const int col  = lane & 15, q = lane >> 4;
  const int s    = blockIdx.x & 1;                 // stack parity -> XCD parity
  const int b0   = (blockIdx.x >> 1) * BW;

  const float* Wih0 = s ? g2_Wih0 : g1_Wih0;
  const float* bih0 = s ? g2_bih0 : g1_bih0;
  const float* bhh0 = s ? g2_bhh0 : g1_bhh0;
  const float* bih1 = s ? g2_bih1 : g1_bih1;
  const float* bhh1 = s ? g2_bhh1 : g1_bhh1;

  const bfrag* W1  = (const bfrag*)(wf + (size_t)s * STACK_W);
  const bfrag* W2I = W1 + W1_ELEMS / 8;
  const bfrag* W2H = W2I + W1_ELEMS / 8;
  const bfrag* B3  = (const bfrag*)(wf + B3_OFF);
  const bfrag* B4  = (const bfrag*)(wf + B4_OFF);

  unsigned short* buf = buf_g + (size_t)s * BATCH * TT * 2 * HH;
  unsigned short* ehb = ehb_g + (size_t)s * BATCH * TT * 2 * HH;
  float* pp = ws_p + (size_t)s * BATCH * TT;

  // Per-lane persistent constants: each wave owns ONE 16-output group nm = wave*16+col
  const int nm0 = wave * 16 + col;
  const float wxr0 = Wih0[nm0 * 2],         wxr1 = Wih0[nm0 * 2 + 1];
  const float wxz0 = Wih0[(256 + nm0) * 2], wxz1 = Wih0[(256 + nm0) * 2 + 1];
  const float wxn0 = Wih0[(512 + nm0) * 2], wxn1 = Wih0[(512 + nm0) * 2 + 1];
  const float br0  = bih0[nm0] + bhh0[nm0];
  const float bz0  = bih0[256 + nm0] + bhh0[256 + nm0];
  const float bni0 = bih0[512 + nm0], bnh0 = bhh0[512 + nm0];
  const float br1  = bih1[nm0] + bhh1[nm0];
  const float bz1  = bih1[256 + nm0] + bhh1[256 + nm0];
  const float bni1 = bih1[512 + nm0], bnh1 = bhh1[512 + nm0];
  const float fcb  = fc_b[nm0];
  const float owv  = out_W[s * HH + nm0];

  // Row layouts (16 rows): hf/hb/hnb = [layer l][batch b] = l*8+b
  //                        es_s      = [b*2+l]
  //                        cacb      = [o*8+b]  (o = layer of h_cat)
  __shared__ float          hf[16 * 260] __attribute__((aligned(16)));
  __shared__ unsigned short hb[16 * 264] __attribute__((aligned(16)));
  __shared__ unsigned short hnb[16 * 264] __attribute__((aligned(16)));
  __shared__ float          es_s[16 * 264] __attribute__((aligned(16)));
  __shared__ unsigned short cacb[16 * 264] __attribute__((aligned(16)));
  __shared__ float          lp[TT * 8 * 2 * 2];      // exp(logit) [j][b][l][o]
  __shared__ float          vw_s[512];               // v_W SWZ'd
  __shared__ float          cpart[2 * 2 * 8 * 256] __attribute__((aligned(16)));  // [jpar][o][b][h]
  __shared__ float          pw_s[16 * 8];            // [wave][b]
  __shared__ float          sinv_s[16];

  for (int x = tid; x < 16 * 260; x += NTHR) hf[x] = 0.0f;
  for (int x = tid; x < 16 * 264; x += NTHR) hb[x] = 0;
  if (tid < 512) { const int o = tid >> 8, g = tid & 255; vw_s[o * 256 + SWZ(g)] = v_W[tid]; }
  __syncthreads();

#pragma unroll 1
  for (int i = 0; i < TT; ++i) {
    // x inputs for this lane's 4 batches (q*4+reg), used in G1 epilogue
    float2 xq[4] = {};
    if (lane < 32) {
#pragma unroll
      for (int reg = 0; reg < 4; reg++)
        xq[reg] = ((const float2*)received)[(size_t)(b0 + q * 4 + reg) * TT + i];
    }

    // ===== G1: gh0 = h0 @ Whh0^T -> layer-0 gates -> hn0 =====
    {
      bfrag a0[8];
#pragma unroll
      for (int c = 0; c < 8; c++)
        a0[c] = (col < BW) ? *(const bfrag*)&hb[col * 264 + c * 32 + q * 8] : zero_frag();
      const int nt16 = wave;
      bfrag bb[24];
#pragma unroll
      for (int c = 0; c < 8; c++) {
        bb[c]      = W1[((nt16 * 3 + 0) * 8 + c) * 64 + lane];
        bb[8 + c]  = W1[((nt16 * 3 + 1) * 8 + c) * 64 + lane];
        bb[16 + c] = W1[((nt16 * 3 + 2) * 8 + c) * 64 + lane];
      }
      f4 aR = {0, 0, 0, 0}, aZ = {0, 0, 0, 0}, aN = {0, 0, 0, 0};
#pragma unroll
      for (int c = 0; c < 8; c++) {
        aR = mfma16(a0[c], bb[c], aR);
        aZ = mfma16(a0[c], bb[8 + c], aZ);
        aN = mfma16(a0[c], bb[16 + c], aN);
      }
      if (lane < 32) {   // C rows 0..7 = batches
#pragma unroll
        for (int reg = 0; reg < 4; reg++) {
          const int b = q * 4 + reg;
          const float rr = sigf(xq[reg].x * wxr0 + xq[reg].y * wxr1 + br0 + aR[reg]);
          const float zz = sigf(xq[reg].x * wxz0 + xq[reg].y * wxz1 + bz0 + aZ[reg]);
          const float nn = tanh_fast(xq[reg].x * wxn0 + xq[reg].y * wxn1 + bni0 +
                                     rr * (aN[reg] + bnh0));
          const float hn0 = (1.0f - zz) * nn + zz * hf[b * 260 + nm0];
          const unsigned short hv = f2bf(hn0);
          hnb[b * 264 + nm0] = hv;
          buf[((size_t)(b0 + b) * (TT * 2) + i * 2 + 0) * HH + nm0] = hv;
        }
      }
    }
    __syncthreads();

    // ===== G2: gi1 + gh1 -> layer-1 gates -> hn1 + pp partial =====
    {
      bfrag ai[8], ah[8];
#pragma unroll
      for (int c = 0; c < 8; c++) {
        ai[c] = (col < BW) ? *(const bfrag*)&hnb[col * 264 + c * 32 + q * 8] : zero_frag();
        ah[c] = (col < BW) ? *(const bfrag*)&hb[(8 + col) * 264 + c * 32 + q * 8] : zero_frag();
      }
      float pv[4] = {0.f, 0.f, 0.f, 0.f};
      const int nt16 = wave;
      bfrag bb[24];
#pragma unroll
      for (int c = 0; c < 8; c++) {
        bb[c]      = W2I[((nt16 * 3 + 0) * 8 + c) * 64 + lane];
        bb[8 + c]  = W2I[((nt16 * 3 + 1) * 8 + c) * 64 + lane];
        bb[16 + c] = W2I[((nt16 * 3 + 2) * 8 + c) * 64 + lane];
      }
      f4 iR = {0, 0, 0, 0}, iZ = {0, 0, 0, 0}, iN = {0, 0, 0, 0};
#pragma unroll
      for (int c = 0; c < 8; c++) {
        iR = mfma16(ai[c], bb[c], iR);
        iZ = mfma16(ai[c], bb[8 + c], iZ);
        iN = mfma16(ai[c], bb[16 + c], iN);
      }
#pragma unroll
      for (int c = 0; c < 8; c++) {
        bb[c]      = W2H[((nt16 * 3 + 0) * 8 + c) * 64 + lane];
        bb[8 + c]  = W2H[((nt16 * 3 + 1) * 8 + c) * 64 + lane];
        bb[16 + c] = W2H[((nt16 * 3 + 2) * 8 + c) * 64 + lane];
      }
      f4 hR = {0, 0, 0, 0}, hZ = {0, 0, 0, 0}, hN = {0, 0, 0, 0};
#pragma unroll
      for (int c = 0; c < 8; c++) {
        hR = mfma16(ah[c], bb[c], hR);
        hZ = mfma16(ah[c], bb[8 + c], hZ);
        hN = mfma16(ah[c], bb[16 + c], hN);
      }
      if (lane < 32) {
#pragma unroll
        for (int reg = 0; reg < 4; reg++) {
          const int b = q * 4 + reg;
          const float rr = sigf(iR[reg] + hR[reg] + br1);
          const float zz = sigf(iZ[reg] + hZ[reg] + bz1);
          const float nn = tanh_fast(iN[reg] + bni1 + rr * (hN[reg] + bnh1));
          const float hn1 = (1.0f - zz) * nn + zz * hf[(8 + b) * 260 + nm0];
          const unsigned short hv = f2bf(hn1);
          hnb[(8 + b) * 264 + nm0] = hv;
          buf[((size_t)(b0 + b) * (TT * 2) + i * 2 + 1) * HH + nm0] = hv;
          pv[reg] += hn1 * owv;
        }
      }
#pragma unroll
      for (int reg = 0; reg < 4; reg++) {
#pragma unroll
        for (int d = 1; d < 16; d <<= 1) pv[reg] += __shfl_xor(pv[reg], d, 64);
      }
      if (col == 0 && q < 2) {
#pragma unroll
        for (int reg = 0; reg < 4; reg++) pw_s[wave * 8 + q * 4 + reg] = pv[reg];
      }
    }
    __syncthreads();

    // ===== G3: es/eh projections (full M=16: rows l*8+b); pp fold =====
    {
      bfrag a3[8];
#pragma unroll
      for (int c = 0; c < 8; c++)
        a3[c] = *(const bfrag*)&hnb[col * 264 + c * 32 + q * 8];
#pragma unroll
      for (int tt = 0; tt < 2; tt++) {
        const int t = wave * 2 + tt;
        bfrag bb[8];
#pragma unroll
        for (int c = 0; c < 8; c++) bb[c] = B3[(t * 8 + c) * 64 + lane];
        f4 acc = {0, 0, 0, 0};
#pragma unroll
        for (int c = 0; c < 8; c++) acc = mfma16(a3[c], bb[c], acc);
        {
          const int n = t * 16 + col;
#pragma unroll
          for (int reg = 0; reg < 4; reg++) {
            const int m = q * 4 + reg;   // 0..15 = l*8+b
            const int l = m >> 3, b = m & 7;
            if (t < 16) es_s[(b * 2 + l) * 264 + SWZ(n)] = acc[reg];
            else ehb[((size_t)(b0 + b) * (TT * 2) + i * 2 + l) * HH + (n - 256)] = f2bf(acc[reg]);
          }
        }
      }
      if (tid < 8) {
        float ss = 0.0f;
#pragma unroll
        for (int w = 0; w < 16; w++) ss += pw_s[w * 8 + tid];
        pp[(size_t)(b0 + tid) * TT + i] = ss;
      }
    }
    __syncthreads();

    // ===== energy: exp(sum_g v*tanh(es+eh)) with 2-stage load pipeline =====
    // slot bits: [2:0]=g8, [5:3]=b, [6]=l, [12:7]=j
    {
      const int nslot = 128 * (i + 1);
      int slot = tid;
      uv4 cur[4];
      if (slot < nslot) {
        const uv4* ep = (const uv4*)(ehb + ((size_t)(b0 + ((slot >> 3) & 7)) * (TT * 2) +
                                            (slot >> 7) * 2 + ((slot >> 6) & 1)) * HH + (slot & 7) * 32);
#pragma unroll
        for (int u = 0; u < 4; u++) cur[u] = __builtin_nontemporal_load(ep + u);
      }
      for (; slot < nslot; slot += NTHR) {
        const int snext = slot + NTHR;
        uv4 nxt[4];
        if (snext < nslot) {
          const uv4* ep2 = (const uv4*)(ehb + ((size_t)(b0 + ((snext >> 3) & 7)) * (TT * 2) +
                                               (snext >> 7) * 2 + ((snext >> 6) & 1)) * HH + (snext & 7) * 32);
#pragma unroll
          for (int u = 0; u < 4; u++) nxt[u] = __builtin_nontemporal_load(ep2 + u);
        } else {
#pragma unroll
          for (int u = 0; u < 4; u++) nxt[u] = cur[u];
        }
        const int g8 = slot & 7;
        const int b  = (slot >> 3) & 7;
        const int l  = (slot >> 6) & 1;
        const int j  = slot >> 7;
        const int eb = (b * 2 + l) * 264;
        float l0 = 0.0f, l1 = 0.0f;
#pragma unroll
        for (int u = 0; u < 4; u++) {
#pragma unroll
          for (int k = 0; k < 4; k++) {
            const int m = u * 8 + k * 2;
            const float e0 = tanh_fast(es_s[eb + (m * 8 + g8)] + bf_lo(cur[u][k]));
            const float e1 = tanh_fast(es_s[eb + ((m + 1) * 8 + g8)] + bf_hi(cur[u][k]));
            l0 = fmaf(e0, vw_s[m * 8 + g8], fmaf(e1, vw_s[(m + 1) * 8 + g8], l0));
            l1 = fmaf(e0, vw_s[256 + m * 8 + g8], fmaf(e1, vw_s[256 + (m + 1) * 8 + g8], l1));
          }
        }
#pragma unroll
        for (int d = 1; d < 8; d <<= 1) { l0 += __shfl_xor(l0, d, 64); l1 += __shfl_xor(l1, d, 64); }
        if (g8 == 0) {
          lp[((j * 8 + b) * 2 + l) * 2 + 0] = __expf(l0);
          lp[((j * 8 + b) * 2 + l) * 2 + 1] = __expf(l1);
        }
#pragma unroll
        for (int u = 0; u < 4; u++) cur[u] = nxt[u];
      }
    }
    __syncthreads();

    // ===== sinv (all 16 waves) + context (uint2 loads, 2-way j-split, lookahead) =====
    {
      {
        const int b = wave >> 1, o = wave & 1;
        const int jl2 = 2 * (i + 1);
        const int jl0 = lane, jl1 = lane + 64;
        float sa = 0.0f;
        if (jl0 < jl2) sa += lp[((jl0 >> 1) * 8 + b) * 4 + (jl0 & 1) * 2 + o];
        if (jl1 < jl2) sa += lp[((jl1 >> 1) * 8 + b) * 4 + (jl1 & 1) * 2 + o];
#pragma unroll
        for (int d = 1; d < 64; d <<= 1) sa += __shfl_xor(sa, d, 64);
        if (lane == 0) sinv_s[b * 2 + o] = rcpf(sa);
      }
      const int h4   = tid & 63;           // uint2 slice (4 h-values)
      const int jpar = (tid >> 6) & 1;     // j mod 2
      const int cb   = tid >> 7;           // batch 0..7
      const uv2* bp = (const uv2*)(buf + ((size_t)(b0 + cb) * (TT * 2)) * HH);
      float c00 = 0.f, c01 = 0.f, c02 = 0.f, c03 = 0.f;
      float c10 = 0.f, c11 = 0.f, c12 = 0.f, c13 = 0.f;
      uv2 aj0 = {0, 0}, aj1 = {0, 0}, bj0 = {0, 0}, bj1 = {0, 0};
      int j = jpar;
      if (j <= i) {
        aj0 = __builtin_nontemporal_load(bp + (j * 2 + 0) * 64 + h4);
        aj1 = __builtin_nontemporal_load(bp + (j * 2 + 1) * 64 + h4);
        // prefetch j+2 (address valid inside workspace even past i)
        bj0 = __builtin_nontemporal_load(bp + ((j + 2) * 2 + 0) * 64 + h4);
        bj1 = __builtin_nontemporal_load(bp + ((j + 2) * 2 + 1) * 64 + h4);
      }
      for (; j <= i; j += 2) {
        uv2 cj0 = {0, 0}, cj1 = {0, 0};
        if (j + 4 <= i) {
          cj0 = __builtin_nontemporal_load(bp + ((j + 4) * 2 + 0) * 64 + h4);
          cj1 = __builtin_nontemporal_load(bp + ((j + 4) * 2 + 1) * 64 + h4);
        }
#pragma unroll
        for (int l = 0; l < 2; l++) {
          const uv2 u = l ? aj1 : aj0;
          const float e0 = lp[((j * 8 + cb) * 2 + l) * 2 + 0];
          const float e1 = lp[((j * 8 + cb) * 2 + l) * 2 + 1];
          const float v0 = bf_lo(u[0]), v1 = bf_hi(u[0]);
          const float v2 = bf_lo(u[1]), v3 = bf_hi(u[1]);
          c00 = fmaf(e0, v0, c00); c01 = fmaf(e0, v1, c01);
          c02 = fmaf(e0, v2, c02); c03 = fmaf(e0, v3, c03);
          c10 = fmaf(e1, v0, c10); c11 = fmaf(e1, v1, c11);
          c12 = fmaf(e1, v2, c12); c13 = fmaf(e1, v3, c13);
        }
        aj0 = bj0; aj1 = bj1; bj0 = cj0; bj1 = cj1;
      }
      ((float4*)&cpart[((jpar * 2 + 0) * 8 + cb) * 256])[h4] = make_float4(c00, c01, c02, c03);
      ((float4*)&cpart[((jpar * 2 + 1) * 8 + cb) * 256])[h4] = make_float4(c10, c11, c12, c13);
    }
    __syncthreads();

    // ===== fold context halves, normalize -> cacb bf16 =====
    for (int x = tid; x < 2 * BW * HH; x += NTHR) {
      const int g = x & 255, b = (x >> 8) & 7, o = x >> 11;
      const float v = (cpart[((0 * 2 + o) * 8 + b) * 256 + g] +
                       cpart[((1 * 2 + o) * 8 + b) * 256 + g]) *
                      sinv_s[b * 2 + o];
      cacb[(o * 8 + b) * 264 + g] = f2bf(v);
    }
    __syncthreads();

    // ===== G4: h = [cac|hn] @ fc_W^T + fc_b (K=512, full M=16) -> new carry =====
    {
      bfrag a4[16];
#pragma unroll
      for (int c = 0; c < 8; c++) {
        a4[c]     = *(const bfrag*)&cacb[col * 264 + c * 32 + q * 8];
        a4[c + 8] = *(const bfrag*)&hnb[col * 264 + c * 32 + q * 8];
      }
      const int t16 = wave;
      bfrag bb[16];
#pragma unroll
      for (int c = 0; c < 16; c++) bb[c] = B4[(t16 * 16 + c) * 64 + lane];
      f4 acc = {0, 0, 0, 0};
#pragma unroll
      for (int c = 0; c < 16; c++) acc = mfma16(a4[c], bb[c], acc);
      {
#pragma unroll
        for (int reg = 0; reg < 4; reg++) {
          const int m = q * 4 + reg;   // 0..15 = l*8+b
          const float v = acc[reg] + fcb;
          hf[m * 260 + nm0] = v;
          hb[m * 264 + nm0] = f2bf(v);
        }
      }
    }
    __syncthreads();
  }
}

__global__ __launch_bounds__(256) void final_combine(const float* __restrict__ ws_p,
                                                     const float* __restrict__ out_b,
                                                     float* __restrict__ out) {
  const int gidx = blockIdx.x * blockDim.x + threadIdx.x;
  if (gidx >= BATCH * TT) return;
  const int b = gidx >> 6;
  const int t = gidx & 63;
  const int idx = (t >= TT - DD - 1) ? (TT - 1) : (t + DD);
  const float* p1 = ws_p;
  const float* p2 = ws_p + (size_t)BATCH * TT;
  const float v = p1[(size_t)b * TT + t] + p2[(size_t)b * TT + idx] + out_b[0];
  out[gidx] = 1.0f / (1.0f + __expf(-v));
}

extern "C" void kernel_launch(void* const* d_in, const int* in_sizes, int n_in,
                              void* d_out, int out_size, void* d_ws, size_t ws_size,
                              hipStream_t stream) {
  const float* received = (const float*)d_in[0];
  const float* g1_Wih0 = (const float*)d_in[1];
  const float* g1_Whh0 = (const float*)d_in[2];
  const float* g1_bih0 = (const float*)d_in[3];
  const float* g1_bhh0 = (const float*)d_in[4];
  const float* g1_Wih1 = (const float*)d_in[5];
  const float* g1_Whh1 = (const float*)d_in[6];
  const float* g1_bih1 = (const float*)d_in[7];
  const float* g1_bhh1 = (const float*)d_in[8];
  const float* g2_Wih0 = (const float*)d_in[9];
  const float* g2_Whh0 = (const float*)d_in[10];
  const float* g2_bih0 = (const float*)d_in[11];
  const float* g2_bhh0 = (const float*)d_in[12];
  const float* g2_Wih1 = (const float*)d_in[13];
  const float* g2_Whh1 = (const float*)d_in[14];
  const float* g2_bih1 = (const float*)d_in[15];
  const float* g2_bhh1 = (const float*)d_in[16];
  const float* fc_W   = (const float*)d_in[17];
  const float* fc_b   = (const float*)d_in[18];
  const float* attn_W = (const float*)d_in[19];
  const float* v_W    = (const float*)d_in[20];
  const float* out_W  = (const float*)d_in[21];
  const float* out_b  = (const float*)d_in[22];

  // ws layout: fp32 pp[2*B*T] | bf16 buf[2*B*T*2*H] | bf16 ehb[same] | bf16 wf[WF_TOTAL]
  float* ws_p = (float*)d_ws;
  unsigned short* buf = (unsigned short*)(ws_p + 2 * BATCH * TT);
  unsigned short* ehb = buf + (size_t)2 * BATCH * TT * 2 * HH;
  unsigned short* wf  = ehb + (size_t)2 * BATCH * TT * 2 * HH;

  hipLaunchKernelGGL(prep_weights, dim3((WF_TOTAL + 255) / 256), dim3(256), 0, stream,
                     g1_Whh0, g1_Wih1, g1_Whh1, g2_Whh0, g2_Wih1, g2_Whh1,
                     attn_W, fc_W, wf);

  hipLaunchKernelGGL(gru_attn, dim3(NBLK), dim3(NTHR), 0, stream,
                     received,
                     g1_Wih0, g1_bih0, g1_bhh0, g1_bih1, g1_bhh1,
                     g2_Wih0, g2_bih0, g2_bhh0, g2_bih1, g2_bhh1,
                     fc_b, v_W, out_W, wf, buf, ehb, ws_p);

  hipLaunchKernelGGL(final_combine, dim3((BATCH * TT + 255) / 256), dim3(256), 0, stream,
                     ws_p, out_b, (float*)d_out);
}

// Round 3
// 5565.383 us; speedup vs baseline: 1.1810x; 1.1810x over previous
//
#include <hip/hip_runtime.h>

// Problem constants
#define BATCH 256
#define TT    64
#define HH    256
#define DD    8

// Tiling: 2 stacks * 64 batch-blocks of BW=4 -> 128 WGs, 1024 thr (16 waves)
// Cache routing (round 3): weights = normal allocating loads (L2-resident,
// 1.66 MB/XCD); history buf/ehb = non-temporal on BOTH store and load sides
// so the growing history stream stops evicting the weight set from L2.
#define BW    4
#define NTHR  1024
#define NBLK  (2 * (BATCH / BW))

typedef __attribute__((ext_vector_type(8))) short bfrag;   // 8 bf16 (MFMA A/B operand)
typedef __attribute__((ext_vector_type(4))) float f4;      // MFMA C/D
typedef __attribute__((ext_vector_type(4))) unsigned int uv4;
typedef __attribute__((ext_vector_type(2))) unsigned int uv2;

#define SWZ(g) ((((g) & 31) << 3) | ((g) >> 5))

__device__ __forceinline__ float rcpf(float x) { return __builtin_amdgcn_rcpf(x); }
__device__ __forceinline__ float sigf(float x) { return rcpf(1.0f + __expf(-x)); }
__device__ __forceinline__ float tanh_fast(float x) {
  const float e = __expf(-2.0f * x);
  return __builtin_fmaf(2.0f, rcpf(1.0f + e), -1.0f);
}
__device__ __forceinline__ unsigned short f2bf(float f) {
  union { float f; unsigned int u; } v; v.f = f;
  return (unsigned short)((v.u + 0x7fffu + ((v.u >> 16) & 1u)) >> 16);
}
__device__ __forceinline__ float bf_lo(unsigned int u) {
  union { unsigned int u; float f; } v; v.u = u << 16; return v.f;
}
__device__ __forceinline__ float bf_hi(unsigned int u) {
  union { unsigned int u; float f; } v; v.u = u & 0xffff0000u; return v.f;
}
__device__ __forceinline__ bfrag zero_frag() {
  bfrag r;
#pragma unroll
  for (int x = 0; x < 8; x++) r[x] = 0;
  return r;
}
__device__ __forceinline__ f4 mfma16(bfrag a, bfrag b, f4 c) {
  return __builtin_amdgcn_mfma_f32_16x16x32_bf16(a, b, c, 0, 0, 0);
}

// ---------- weight fragment layout (UNCHANGED) ----------
#define W1_ELEMS  196608
#define STACK_W   (3 * W1_ELEMS)
#define B3_OFF    (2 * STACK_W)
#define B4_OFF    (B3_OFF + 131072)
#define WF_TOTAL  (B4_OFF + 131072)

__global__ __launch_bounds__(256) void prep_weights(
    const float* __restrict__ g1_Whh0, const float* __restrict__ g1_Wih1, const float* __restrict__ g1_Whh1,
    const float* __restrict__ g2_Whh0, const float* __restrict__ g2_Wih1, const float* __restrict__ g2_Whh1,
    const float* __restrict__ attn_W, const float* __restrict__ fc_W,
    unsigned short* __restrict__ wf) {
  const int id = blockIdx.x * 256 + threadIdx.x;
  if (id >= WF_TOTAL) return;
  float src;
  if (id < 2 * STACK_W) {
    const int s = id / STACK_W, r = id % STACK_W;
    const int mm = r / W1_ELEMS, e = r % W1_ELEMS;
    const int j = e & 7, lane = (e >> 3) & 63, c = (e >> 9) & 7, t = e >> 12;
    const int nt = t / 3, g = t % 3;
    const int n = nt * 16 + (lane & 15);
    const int k = c * 32 + ((lane >> 4) << 3) + j;
    const float* W = (mm == 0) ? (s ? g2_Whh0 : g1_Whh0)
                   : (mm == 1) ? (s ? g2_Wih1 : g1_Wih1)
                               : (s ? g2_Whh1 : g1_Whh1);
    src = W[(g * 256 + n) * 256 + k];
  } else if (id < B4_OFF) {
    const int e = id - B3_OFF;
    const int j = e & 7, lane = (e >> 3) & 63, c = (e >> 9) & 7, t = e >> 12;
    const int n = t * 16 + (lane & 15);
    const int k = c * 32 + ((lane >> 4) << 3) + j;
    src = (n < 256) ? attn_W[n * 512 + k] : attn_W[(n - 256) * 512 + 256 + k];
  } else {
    const int e = id - B4_OFF;
    const int j = e & 7, lane = (e >> 3) & 63, c = (e >> 9) & 15, t = e >> 13;
    const int n = t * 16 + (lane & 15);
    const int k = c * 32 + ((lane >> 4) << 3) + j;
    src = fc_W[n * 512 + k];
  }
  wf[id] = f2bf(src);
}

__global__ __launch_bounds__(NTHR, 4) void gru_attn(
    const float* __restrict__ received,
    const float* __restrict__ g1_Wih0, const float* __restrict__ g1_bih0, const float* __restrict__ g1_bhh0,
    const float* __restrict__ g1_bih1, const float* __restrict__ g1_bhh1,
    const float* __restrict__ g2_Wih0, const float* __restrict__ g2_bih0, const float* __restrict__ g2_bhh0,
    const float* __restrict__ g2_bih1, const float* __restrict__ g2_bhh1,
    const float* __restrict__ fc_b, const float* __restrict__ v_W, const float* __restrict__ out_W,
    const unsigned short* __restrict__ wf,
    unsigned short* __restrict__ buf_g, unsigned short* __restrict__ ehb_g,
    float* __restrict__ ws_p) {
  const int tid  = threadIdx.x;
  const int lane = tid & 63, wave = tid >> 6;      // 16 waves
  const int col  = lane & 15, q = lane >> 4;
  const int s    = blockIdx.x & 1;                 // stack parity -> XCD parity
  const int b0   = (blockIdx.x >> 1) * BW;

  const float* Wih0 = s ? g2_Wih0 : g1_Wih0;
  const float* bih0 = s ? g2_bih0 : g1_bih0;
  const float* bhh0 = s ? g2_bhh0 : g1_bhh0;
  const float* bih1 = s ? g2_bih1 : g1_bih1;
  const float* bhh1 = s ? g2_bhh1 : g1_bhh1;

  const bfrag* W1  = (const bfrag*)(wf + (size_t)s * STACK_W);
  const bfrag* W2I = W1 + W1_ELEMS / 8;
  const bfrag* W2H = W2I + W1_ELEMS / 8;
  const bfrag* B3  = (const bfrag*)(wf + B3_OFF);
  const bfrag* B4  = (const bfrag*)(wf + B4_OFF);

  unsigned short* buf = buf_g + (size_t)s * BATCH * TT * 2 * HH;
  unsigned short* ehb = ehb_g + (size_t)s * BATCH * TT * 2 * HH;
  float* pp = ws_p + (size_t)s * BATCH * TT;

  // Per-lane persistent constants: each wave owns ONE 16-output group nm = wave*16+col
  const int nm0 = wave * 16 + col;
  const float wxr0 = Wih0[nm0 * 2],         wxr1 = Wih0[nm0 * 2 + 1];
  const float wxz0 = Wih0[(256 + nm0) * 2], wxz1 = Wih0[(256 + nm0) * 2 + 1];
  const float wxn0 = Wih0[(512 + nm0) * 2], wxn1 = Wih0[(512 + nm0) * 2 + 1];
  const float br0  = bih0[nm0] + bhh0[nm0];
  const float bz0  = bih0[256 + nm0] + bhh0[256 + nm0];
  const float bni0 = bih0[512 + nm0], bnh0 = bhh0[512 + nm0];
  const float br1  = bih1[nm0] + bhh1[nm0];
  const float bz1  = bih1[256 + nm0] + bhh1[256 + nm0];
  const float bni1 = bih1[512 + nm0], bnh1 = bhh1[512 + nm0];
  const float fcb  = fc_b[nm0];
  const float owv  = out_W[s * HH + nm0];

  __shared__ float          hf[8 * 260] __attribute__((aligned(16)));
  __shared__ unsigned short hb[8 * 264] __attribute__((aligned(16)));
  __shared__ unsigned short hnb[8 * 264] __attribute__((aligned(16)));
  __shared__ float          es_s[8 * 264] __attribute__((aligned(16)));
  __shared__ unsigned short cacb[8 * 264] __attribute__((aligned(16)));
  __shared__ float          lp[TT * 4 * 2 * 2];       // exp(logit) [j][b][l][o]
  __shared__ float          vw_s[512];                // v_W SWZ'd
  __shared__ float          cpart[4 * 2 * 4 * 256] __attribute__((aligned(16)));  // [jpar][o][b][h]
  __shared__ float          pw_s[64];                 // [wave][b]
  __shared__ float          sinv_s[8];

  for (int x = tid; x < 8 * 260; x += NTHR) hf[x] = 0.0f;
  for (int x = tid; x < 8 * 264; x += NTHR) hb[x] = 0;
  if (tid < 512) { const int o = tid >> 8, g = tid & 255; vw_s[o * 256 + SWZ(g)] = v_W[tid]; }
  __syncthreads();

#pragma unroll 1
  for (int i = 0; i < TT; ++i) {
    float2 xv[BW];
#pragma unroll
    for (int b = 0; b < BW; b++) xv[b] = ((const float2*)received)[(size_t)(b0 + b) * TT + i];

    // ===== G1: gh0 = h0 @ Whh0^T -> layer-0 gates -> hn0 =====
    {
      bfrag a0[8];
#pragma unroll
      for (int c = 0; c < 8; c++)
        a0[c] = (col < BW) ? *(const bfrag*)&hb[col * 264 + c * 32 + q * 8] : zero_frag();
      const int nt16 = wave;
      bfrag bb[24];
#pragma unroll
      for (int c = 0; c < 8; c++) {
        bb[c]      = W1[((nt16 * 3 + 0) * 8 + c) * 64 + lane];
        bb[8 + c]  = W1[((nt16 * 3 + 1) * 8 + c) * 64 + lane];
        bb[16 + c] = W1[((nt16 * 3 + 2) * 8 + c) * 64 + lane];
      }
      f4 aR = {0, 0, 0, 0}, aZ = {0, 0, 0, 0}, aN = {0, 0, 0, 0};
#pragma unroll
      for (int c = 0; c < 8; c++) {
        aR = mfma16(a0[c], bb[c], aR);
        aZ = mfma16(a0[c], bb[8 + c], aZ);
        aN = mfma16(a0[c], bb[16 + c], aN);
      }
      if (lane < 16) {
#pragma unroll
        for (int reg = 0; reg < 4; reg++) {
          const int b = reg;
          const float rr = sigf(xv[b].x * wxr0 + xv[b].y * wxr1 + br0 + aR[reg]);
          const float zz = sigf(xv[b].x * wxz0 + xv[b].y * wxz1 + bz0 + aZ[reg]);
          const float nn = tanh_fast(xv[b].x * wxn0 + xv[b].y * wxn1 + bni0 +
                                     rr * (aN[reg] + bnh0));
          const float hn0 = (1.0f - zz) * nn + zz * hf[b * 260 + nm0];
          const unsigned short hv = f2bf(hn0);
          hnb[b * 264 + nm0] = hv;
          __builtin_nontemporal_store(hv,
              &buf[((size_t)(b0 + b) * (TT * 2) + i * 2 + 0) * HH + nm0]);
        }
      }
    }
    __syncthreads();

    // ===== G2: gi1 + gh1 -> layer-1 gates -> hn1 + pp partial =====
    {
      bfrag ai[8], ah[8];
#pragma unroll
      for (int c = 0; c < 8; c++) {
        ai[c] = (col < BW) ? *(const bfrag*)&hnb[col * 264 + c * 32 + q * 8] : zero_frag();
        ah[c] = (col < BW) ? *(const bfrag*)&hb[(4 + col) * 264 + c * 32 + q * 8] : zero_frag();
      }
      float pv[4] = {0.f, 0.f, 0.f, 0.f};
      const int nt16 = wave;
      bfrag bb[24];
#pragma unroll
      for (int c = 0; c < 8; c++) {
        bb[c]      = W2I[((nt16 * 3 + 0) * 8 + c) * 64 + lane];
        bb[8 + c]  = W2I[((nt16 * 3 + 1) * 8 + c) * 64 + lane];
        bb[16 + c] = W2I[((nt16 * 3 + 2) * 8 + c) * 64 + lane];
      }
      f4 iR = {0, 0, 0, 0}, iZ = {0, 0, 0, 0}, iN = {0, 0, 0, 0};
#pragma unroll
      for (int c = 0; c < 8; c++) {
        iR = mfma16(ai[c], bb[c], iR);
        iZ = mfma16(ai[c], bb[8 + c], iZ);
        iN = mfma16(ai[c], bb[16 + c], iN);
      }
#pragma unroll
      for (int c = 0; c < 8; c++) {
        bb[c]      = W2H[((nt16 * 3 + 0) * 8 + c) * 64 + lane];
        bb[8 + c]  = W2H[((nt16 * 3 + 1) * 8 + c) * 64 + lane];
        bb[16 + c] = W2H[((nt16 * 3 + 2) * 8 + c) * 64 + lane];
      }
      f4 hR = {0, 0, 0, 0}, hZ = {0, 0, 0, 0}, hN = {0, 0, 0, 0};
#pragma unroll
      for (int c = 0; c < 8; c++) {
        hR = mfma16(ah[c], bb[c], hR);
        hZ = mfma16(ah[c], bb[8 + c], hZ);
        hN = mfma16(ah[c], bb[16 + c], hN);
      }
      if (lane < 16) {
#pragma unroll
        for (int reg = 0; reg < 4; reg++) {
          const int b = reg;
          const float rr = sigf(iR[reg] + hR[reg] + br1);
          const float zz = sigf(iZ[reg] + hZ[reg] + bz1);
          const float nn = tanh_fast(iN[reg] + bni1 + rr * (hN[reg] + bnh1));
          const float hn1 = (1.0f - zz) * nn + zz * hf[(4 + b) * 260 + nm0];
          const unsigned short hv = f2bf(hn1);
          hnb[(4 + b) * 264 + nm0] = hv;
          __builtin_nontemporal_store(hv,
              &buf[((size_t)(b0 + b) * (TT * 2) + i * 2 + 1) * HH + nm0]);
          pv[reg] += hn1 * owv;
        }
      }
#pragma unroll
      for (int reg = 0; reg < 4; reg++) {
#pragma unroll
        for (int d = 1; d < 16; d <<= 1) pv[reg] += __shfl_xor(pv[reg], d, 64);
      }
      if (lane == 0) {
#pragma unroll
        for (int reg = 0; reg < 4; reg++) pw_s[wave * 4 + reg] = pv[reg];
      }
    }
    __syncthreads();

    // ===== G3: es/eh projections; pp fold =====
    {
      bfrag a3[8];
#pragma unroll
      for (int c = 0; c < 8; c++)
        a3[c] = (col < 8) ? *(const bfrag*)&hnb[col * 264 + c * 32 + q * 8] : zero_frag();
#pragma unroll
      for (int tt = 0; tt < 2; tt++) {
        const int t = wave * 2 + tt;
        bfrag bb[8];
#pragma unroll
        for (int c = 0; c < 8; c++) bb[c] = B3[(t * 8 + c) * 64 + lane];
        f4 acc = {0, 0, 0, 0};
#pragma unroll
        for (int c = 0; c < 8; c++) acc = mfma16(a3[c], bb[c], acc);
        if (lane < 32) {
          const int n = t * 16 + col;
#pragma unroll
          for (int reg = 0; reg < 4; reg++) {
            const int m = q * 4 + reg;   // 0..7 = l*4+b
            const int l = m >> 2, b = m & 3;
            if (t < 16) es_s[(b * 2 + l) * 264 + SWZ(n)] = acc[reg];
            else __builtin_nontemporal_store(f2bf(acc[reg]),
                &ehb[((size_t)(b0 + b) * (TT * 2) + i * 2 + l) * HH + (n - 256)]);
          }
        }
      }
      if (tid < 4) {
        float ss = 0.0f;
#pragma unroll
        for (int w = 0; w < 16; w++) ss += pw_s[w * 4 + tid];
        pp[(size_t)(b0 + tid) * TT + i] = ss;
      }
    }
    __syncthreads();

    // ===== energy: exp(sum_g v*tanh(es+eh)) with 2-stage load pipeline =====
    {
      const int nslot = 64 * (i + 1);
      int slot = tid;
      uv4 cur[4];
      if (slot < nslot) {
        const uv4* ep = (const uv4*)(ehb + ((size_t)(b0 + ((slot >> 3) & 3)) * (TT * 2) +
                                            (slot >> 6) * 2 + ((slot >> 5) & 1)) * HH + (slot & 7) * 32);
#pragma unroll
        for (int u = 0; u < 4; u++) cur[u] = __builtin_nontemporal_load(ep + u);
      }
      for (; slot < nslot; slot += NTHR) {
        const int snext = slot + NTHR;
        uv4 nxt[4];
        if (snext < nslot) {
          const uv4* ep2 = (const uv4*)(ehb + ((size_t)(b0 + ((snext >> 3) & 3)) * (TT * 2) +
                                               (snext >> 6) * 2 + ((snext >> 5) & 1)) * HH + (snext & 7) * 32);
#pragma unroll
          for (int u = 0; u < 4; u++) nxt[u] = __builtin_nontemporal_load(ep2 + u);
        } else {
#pragma unroll
          for (int u = 0; u < 4; u++) nxt[u] = cur[u];
        }
        const int g8 = slot & 7;
        const int b  = (slot >> 3) & 3;
        const int l  = (slot >> 5) & 1;
        const int j  = slot >> 6;
        const int eb = (b * 2 + l) * 264;
        float l0 = 0.0f, l1 = 0.0f;
#pragma unroll
        for (int u = 0; u < 4; u++) {
#pragma unroll
          for (int k = 0; k < 4; k++) {
            const int m = u * 8 + k * 2;
            const float e0 = tanh_fast(es_s[eb + (m * 8 + g8)] + bf_lo(cur[u][k]));
            const float e1 = tanh_fast(es_s[eb + ((m + 1) * 8 + g8)] + bf_hi(cur[u][k]));
            l0 = fmaf(e0, vw_s[m * 8 + g8], fmaf(e1, vw_s[(m + 1) * 8 + g8], l0));
            l1 = fmaf(e0, vw_s[256 + m * 8 + g8], fmaf(e1, vw_s[256 + (m + 1) * 8 + g8], l1));
          }
        }
#pragma unroll
        for (int d = 1; d < 8; d <<= 1) { l0 += __shfl_xor(l0, d, 64); l1 += __shfl_xor(l1, d, 64); }
        if (g8 == 0) {
          lp[((j * 4 + b) * 2 + l) * 2 + 0] = __expf(l0);
          lp[((j * 4 + b) * 2 + l) * 2 + 1] = __expf(l1);
        }
#pragma unroll
        for (int u = 0; u < 4; u++) cur[u] = nxt[u];
      }
    }
    __syncthreads();

    // ===== sinv (waves 0-7) + context (uint2 loads, 4-way j-split, lookahead) =====
    {
      if (wave < 8) {
        const int b = wave >> 1, o = wave & 1;
        const int jl2 = 2 * (i + 1);
        const int jl0 = lane, jl1 = lane + 64;
        float sa = 0.0f;
        if (jl0 < jl2) sa += lp[((jl0 >> 1) * 4 + b) * 4 + (jl0 & 1) * 2 + o];
        if (jl1 < jl2) sa += lp[((jl1 >> 1) * 4 + b) * 4 + (jl1 & 1) * 2 + o];
#pragma unroll
        for (int d = 1; d < 64; d <<= 1) sa += __shfl_xor(sa, d, 64);
        if (lane == 0) sinv_s[b * 2 + o] = rcpf(sa);
      }
      const int h4   = tid & 63;           // uint2 slice (4 h-values)
      const int jpar = (tid >> 6) & 3;     // j mod 4
      const int cb   = tid >> 8;           // batch 0..3
      const uv2* bp = (const uv2*)(buf + ((size_t)(b0 + cb) * (TT * 2)) * HH);
      float c00 = 0.f, c01 = 0.f, c02 = 0.f, c03 = 0.f;
      float c10 = 0.f, c11 = 0.f, c12 = 0.f, c13 = 0.f;
      uv2 aj0 = {0, 0}, aj1 = {0, 0}, bj0 = {0, 0}, bj1 = {0, 0};
      int j = jpar;
      if (j <= i) {
        aj0 = __builtin_nontemporal_load(bp + (j * 2 + 0) * 64 + h4);
        aj1 = __builtin_nontemporal_load(bp + (j * 2 + 1) * 64 + h4);
        // prefetch j+4 (address always within this batch's buf region)
        bj0 = __builtin_nontemporal_load(bp + ((j + 4) * 2 + 0) * 64 + h4);
        bj1 = __builtin_nontemporal_load(bp + ((j + 4) * 2 + 1) * 64 + h4);
      }
      for (; j <= i; j += 4) {
        uv2 cj0 = {0, 0}, cj1 = {0, 0};
        if (j + 8 <= i) {
          cj0 = __builtin_nontemporal_load(bp + ((j + 8) * 2 + 0) * 64 + h4);
          cj1 = __builtin_nontemporal_load(bp + ((j + 8) * 2 + 1) * 64 + h4);
        }
#pragma unroll
        for (int l = 0; l < 2; l++) {
          const uv2 u = l ? aj1 : aj0;
          const float e0 = lp[((j * 4 + cb) * 2 + l) * 2 + 0];
          const float e1 = lp[((j * 4 + cb) * 2 + l) * 2 + 1];
          const float v0 = bf_lo(u[0]), v1 = bf_hi(u[0]);
          const float v2 = bf_lo(u[1]), v3 = bf_hi(u[1]);
          c00 = fmaf(e0, v0, c00); c01 = fmaf(e0, v1, c01);
          c02 = fmaf(e0, v2, c02); c03 = fmaf(e0, v3, c03);
          c10 = fmaf(e1, v0, c10); c11 = fmaf(e1, v1, c11);
          c12 = fmaf(e1, v2, c12); c13 = fmaf(e1, v3, c13);
        }
        aj0 = bj0; aj1 = bj1; bj0 = cj0; bj1 = cj1;
      }
      ((float4*)&cpart[((jpar * 2 + 0) * 4 + cb) * 256])[h4] = make_float4(c00, c01, c02, c03);
      ((float4*)&cpart[((jpar * 2 + 1) * 4 + cb) * 256])[h4] = make_float4(c10, c11, c12, c13);
    }
    __syncthreads();

    // ===== fold context quarters, normalize -> cacb bf16 =====
    for (int x = tid; x < 2 * BW * HH; x += NTHR) {
      const int g = x & 255, b = (x >> 8) & 3, o = x >> 10;
      const float v = (cpart[((0 * 2 + o) * 4 + b) * 256 + g] +
                       cpart[((1 * 2 + o) * 4 + b) * 256 + g] +
                       cpart[((2 * 2 + o) * 4 + b) * 256 + g] +
                       cpart[((3 * 2 + o) * 4 + b) * 256 + g]) *
                      sinv_s[b * 2 + o];
      cacb[(o * 4 + b) * 264 + g] = f2bf(v);
    }
    __syncthreads();

    // ===== G4: h = [cac|hn] @ fc_W^T + fc_b (K=512) -> new carry =====
    {
      bfrag a4[16];
      if (col < 8) {
#pragma unroll
        for (int c = 0; c < 8; c++) {
          a4[c]     = *(const bfrag*)&cacb[col * 264 + c * 32 + q * 8];
          a4[c + 8] = *(const bfrag*)&hnb[col * 264 + c * 32 + q * 8];
        }
      } else {
#pragma unroll
        for (int c = 0; c < 16; c++) a4[c] = zero_frag();
      }
      const int t16 = wave;
      bfrag bb[16];
#pragma unroll
      for (int c = 0; c < 16; c++) bb[c] = B4[(t16 * 16 + c) * 64 + lane];
      f4 acc = {0, 0, 0, 0};
#pragma unroll
      for (int c = 0; c < 16; c++) acc = mfma16(a4[c], bb[c], acc);
      if (lane < 32) {
#pragma unroll
        for (int reg = 0; reg < 4; reg++) {
          const int m = q * 4 + reg;   // 0..7 = o*4+b
          const float v = acc[reg] + fcb;
          hf[m * 260 + nm0] = v;
          hb[m * 264 + nm0] = f2bf(v);
        }
      }
    }
    __syncthreads();
  }
}

__global__ __launch_bounds__(256) void final_combine(const float* __restrict__ ws_p,
                                                     const float* __restrict__ out_b,
                                                     float* __restrict__ out) {
  const int gidx = blockIdx.x * blockDim.x + threadIdx.x;
  if (gidx >= BATCH * TT) return;
  const int b = gidx >> 6;
  const int t = gidx & 63;
  const int idx = (t >= TT - DD - 1) ? (TT - 1) : (t + DD);
  const float* p1 = ws_p;
  const float* p2 = ws_p + (size_t)BATCH * TT;
  const float v = p1[(size_t)b * TT + t] + p2[(size_t)b * TT + idx] + out_b[0];
  out[gidx] = 1.0f / (1.0f + __expf(-v));
}

extern "C" void kernel_launch(void* const* d_in, const int* in_sizes, int n_in,
                              void* d_out, int out_size, void* d_ws, size_t ws_size,
                              hipStream_t stream) {
  const float* received = (const float*)d_in[0];
  const float* g1_Wih0 = (const float*)d_in[1];
  const float* g1_Whh0 = (const float*)d_in[2];
  const float* g1_bih0 = (const float*)d_in[3];
  const float* g1_bhh0 = (const float*)d_in[4];
  const float* g1_Wih1 = (const float*)d_in[5];
  const float* g1_Whh1 = (const float*)d_in[6];
  const float* g1_bih1 = (const float*)d_in[7];
  const float* g1_bhh1 = (const float*)d_in[8];
  const float* g2_Wih0 = (const float*)d_in[9];
  const float* g2_Whh0 = (const float*)d_in[10];
  const float* g2_bih0 = (const float*)d_in[11];
  const float* g2_bhh0 = (const float*)d_in[12];
  const float* g2_Wih1 = (const float*)d_in[13];
  const float* g2_Whh1 = (const float*)d_in[14];
  const float* g2_bih1 = (const float*)d_in[15];
  const float* g2_bhh1 = (const float*)d_in[16];
  const float* fc_W   = (const float*)d_in[17];
  const float* fc_b   = (const float*)d_in[18];
  const float* attn_W = (const float*)d_in[19];
  const float* v_W    = (const float*)d_in[20];
  const float* out_W  = (const float*)d_in[21];
  const float* out_b  = (const float*)d_in[22];

  // ws layout: fp32 pp[2*B*T] | bf16 buf[2*B*T*2*H] | bf16 ehb[same] | bf16 wf[WF_TOTAL]
  float* ws_p = (float*)d_ws;
  unsigned short* buf = (unsigned short*)(ws_p + 2 * BATCH * TT);
  unsigned short* ehb = buf + (size_t)2 * BATCH * TT * 2 * HH;
  unsigned short* wf  = ehb + (size_t)2 * BATCH * TT * 2 * HH;

  hipLaunchKernelGGL(prep_weights, dim3((WF_TOTAL + 255) / 256), dim3(256), 0, stream,
                     g1_Whh0, g1_Wih1, g1_Whh1, g2_Whh0, g2_Wih1, g2_Whh1,
                     attn_W, fc_W, wf);

  hipLaunchKernelGGL(gru_attn, dim3(NBLK), dim3(NTHR), 0, stream,
                     received,
                     g1_Wih0, g1_bih0, g1_bhh0, g1_bih1, g1_bhh1,
                     g2_Wih0, g2_bih0, g2_bhh0, g2_bih1, g2_bhh1,
                     fc_b, v_W, out_W, wf, buf, ehb, ws_p);

  hipLaunchKernelGGL(final_combine, dim3((BATCH * TT + 255) / 256), dim3(256), 0, stream,
                     ws_p, out_b, (float*)d_out);
}